// Round 8
// baseline (2047.868 us; speedup 1.0000x reference)
//
#include <hip/hip_runtime.h>
#include <hip/hip_bf16.h>

#define T_STEPS 512
#define TS_US   65536         // ushorts per t-slot (128KB) for x and h buffers

typedef __attribute__((ext_vector_type(4))) float f32x4;
typedef __attribute__((ext_vector_type(8))) short s16x8;

// ---------- helpers ----------
__device__ __forceinline__ unsigned short f2bf(float f){
  unsigned int u = __float_as_uint(f);
  unsigned int r = (u + 0x7fffu + ((u >> 16) & 1u)) >> 16;
  return (unsigned short)r;
}
__device__ __forceinline__ float fsig(float x){
  return __builtin_amdgcn_rcpf(1.f + __expf(-x));
}
__device__ __forceinline__ float ftanh(float x){
  x = fminf(fmaxf(x, -15.f), 15.f);
  float a = __expf(2.f * x);
  return (a - 1.f) * __builtin_amdgcn_rcpf(a + 1.f);
}

// ---------- pack x into 16-row (q-group) MFMA A-fragment layout ----------
// xp: [t][q(8)][kt(16)][lane(64)][8] bf16. row = lane&15, k = kt*32+(lane>>4)*8+e.
__global__ void k_pack_x(const float* __restrict__ x, unsigned short* __restrict__ xp){
  int t = blockIdx.x >> 3, q = blockIdx.x & 7;
  __shared__ unsigned short xs[16*520];
  int tid = threadIdx.x;
  for (int qq = tid; qq < 1024; qq += 256){
    int rw = qq >> 6, k8 = qq & 63;
    const float* src = x + ((size_t)(q*16 + rw)*512 + t)*512 + k8*8;
    union { unsigned short u[8]; s16x8 v; } tmp;
#pragma unroll
    for (int e = 0; e < 8; e++) tmp.u[e] = f2bf(src[e]);
    *(s16x8*)&xs[rw*520 + k8*8] = tmp.v;
  }
  __syncthreads();
  for (int s = tid; s < 1024; s += 256){
    int kt = s >> 6, ln = s & 63;
    int rw2 = ln & 15, k0 = kt*32 + (ln >> 4)*8;
    s16x8 v = *(const s16x8*)&xs[rw2*520 + k0];
    ((s16x8*)xp)[(size_t)t*8192 + (q*16 + kt)*64 + ln] = v;
  }
}

// ---------- pack layer-1 weights into B-fragment layout ----------
// wp: [r(32)][ch=kt*4+n (128)][lane(64)][8]; col = n*512 + r*16 + (lane&15),
// k = kt*32 + (lane>>4)*8 + e (kt<16 -> Wi; else Wh row k-512)
__global__ void k_pack_w1(const float* __restrict__ Wi, const float* __restrict__ Wh,
                          const float* __restrict__ b, unsigned short* __restrict__ wp,
                          float* __restrict__ bias){
  int r = blockIdx.x, tid = threadIdx.x;
  int lane = tid & 63, u0 = tid >> 6;
  for (int ch = u0; ch < 128; ch += 4){
    int kt = ch >> 2, n = ch & 3;
    int col = n*512 + r*16 + (lane & 15);
    int kb = kt*32 + (lane >> 4)*8;
    union { unsigned short u[8]; s16x8 v; } tmp;
#pragma unroll
    for (int e = 0; e < 8; e++){
      int k = kb + e;
      float wv = (kt < 16) ? Wi[(size_t)k*2048 + col] : Wh[(size_t)(k-512)*2048 + col];
      tmp.u[e] = f2bf(wv);
    }
    ((s16x8*)wp)[((size_t)r*128 + ch)*64 + lane] = tmp.v;
  }
  if (tid < 64) bias[r*64 + tid] = b[(tid >> 4)*512 + r*16 + (tid & 15)];
}

// ---------- fold BN1 into Wi2, pack layer-2 weights, fused bias ----------
__global__ void k_fold2(const float* __restrict__ Wi2, const float* __restrict__ Wh2,
                        const float* __restrict__ b2, const float* __restrict__ gamma,
                        const float* __restrict__ beta, const float* __restrict__ stats,
                        unsigned short* __restrict__ wp, float* __restrict__ bias){
  __shared__ float a_s[512], c_s[512], red[256];
  int r = blockIdx.x, tid = threadIdx.x;
  for (int k = tid; k < 512; k += 256){
    float sm = 0.f, sq = 0.f;
#pragma unroll
    for (int g = 0; g < 16; g++){ sm += stats[(k*16+g)*2]; sq += stats[(k*16+g)*2+1]; }
    float mean = sm * (1.f/65536.f);
    float var  = sq * (1.f/65536.f) - mean*mean;
    float rr = rsqrtf(fmaxf(var, 0.f) + 1e-5f);
    float a = rr * gamma[k];
    a_s[k] = a; c_s[k] = beta[k] - mean*a;
  }
  __syncthreads();
  int lane = tid & 63, u0 = tid >> 6;
  for (int ch = u0; ch < 128; ch += 4){
    int kt = ch >> 2, n = ch & 3;
    int col = n*512 + r*16 + (lane & 15);
    int kb = kt*32 + (lane >> 4)*8;
    union { unsigned short u[8]; s16x8 v; } tmp;
#pragma unroll
    for (int e = 0; e < 8; e++){
      int k = kb + e;
      float wv = (kt < 16) ? a_s[k]*Wi2[(size_t)k*2048 + col]
                           : Wh2[(size_t)(k-512)*2048 + col];
      tmp.u[e] = f2bf(wv);
    }
    ((s16x8*)wp)[((size_t)r*128 + ch)*64 + lane] = tmp.v;
  }
  int colj = tid >> 2, part = tid & 3;
  int n = colj >> 4, cl = colj & 15;
  int col = n*512 + r*16 + cl;
  float s = 0.f;
  for (int k = part*128; k < part*128 + 128; k++) s += c_s[k]*Wi2[(size_t)k*2048 + col];
  red[tid] = s;
  __syncthreads();
  if (part == 0)
    bias[r*64 + colj] = b2[col] + red[tid] + red[tid+1] + red[tid+2] + red[tid+3];
}

__global__ void k_reset(int* f1, int* f2, int* x1, int* x2){
  int t = threadIdx.x;
  for (int i = t; i < 8192; i += 1024){ f1[i] = 0; f2[i] = 0; }
  for (int i = t; i < 2048; i += 1024){ x1[i] = 0; x2[i] = 0; }
}

__global__ void k_sentinel(float* out, int n, float v){
  int i = blockIdx.x * blockDim.x + threadIdx.x;
  if (i < n) out[i] = v;
}

// ---------- persistent group-local LSTM scan (TLP edition) ----------
// 512 blocks x 256 threads. 16 groups x 8 batch rows; gg = blockIdx&15,
// r = blockIdx>>4 -> a group's 32 ranks share XCD gg%8, and each XCD hosts
// TWO independent groups on its 32 CUs -> 2 blocks/CU: when one group's
// block stalls on sync, the co-resident block computes (TLP latency hiding).
// __launch_bounds__(256,2) caps regs so 2 blocks/CU are allocatable (all 512
// blocks MUST be resident; valves keep any failure diagnostic, not hanging).
// A-tiles stay 16 rows (8 real + discarded garbage rows). h-exchange stores
// only the 8 real rows: [t][gg(16)][kt(16)][sl(32)][8] bf16 where
// sl = row(0-7) + 8*(k>>3 within ktile); readers duplicate-map rows 8-15.
// Gates/publish: waves 0-1 only (tid<128: rl=tid&7, cl=tid>>3).
// Flag/consensus machinery identical to round 7 (probed nt fast path).
template<int LAYER>
__global__ __launch_bounds__(256, 2)
void k_scan(const unsigned short* __restrict__ xin, unsigned short* __restrict__ hex,
            const unsigned short* __restrict__ wp, const float* __restrict__ bias,
            int* __restrict__ flags, int* __restrict__ xmap, float* __restrict__ aux){
  __shared__ __align__(16) float zs[2][4*64*20];   // double-buffered zones
  __shared__ float blds[64];
  __shared__ int s_mode;
  int gg = blockIdx.x & 15, r = blockIdx.x >> 4;
  int q = gg >> 1, odd = gg & 1;
  int tid = threadIdx.x, w = tid >> 6, lane = tid & 63;

  // weight fragments -> registers/AGPRs (volatile: load exactly once)
  const volatile s16x8* wpv = (const volatile s16x8*)((const s16x8*)wp + (size_t)r*128*64);
  s16x8 B[8][4];
#pragma unroll
  for (int ki = 0; ki < 8; ki++){
    int kt = (ki < 4) ? (4*w + ki) : (12 + 4*w + ki);
#pragma unroll
    for (int n = 0; n < 4; n++)
      B[ki][n] = wpv[((size_t)kt*4 + n)*64 + lane];
  }
  if (tid < 64) blds[tid] = bias[r*64 + tid];

  // ---- stage 1: XCD uniformity handshake ----
  int myx;
  asm volatile("s_getreg_b32 %0, hwreg(HW_REG_XCC_ID)" : "=s"(myx));
  if (tid == 0)
    __hip_atomic_store(&xmap[gg*32 + r], (myx & 0xff) + 1, __ATOMIC_RELAXED, __HIP_MEMORY_SCOPE_AGENT);
  int xv, hb = 0;
  for (;;){
    xv = __hip_atomic_load(&xmap[gg*32 + (lane & 31)], __ATOMIC_RELAXED, __HIP_MEMORY_SCOPE_AGENT);
    if (__all(xv != 0)) break;
    __builtin_amdgcn_s_sleep(2);
    if (++hb > (1<<16)) break;
  }
  int xv0 = __builtin_amdgcn_readfirstlane(xv);
  bool fastp = __all(xv != 0 && xv == xv0) != 0;

  // ---- stage 2: nt-visibility probe ----
  int ntok = 0;
  if (fastp){
    if (tid == 0)
      __hip_atomic_store(&xmap[512 + gg*32 + r], r + 1, __ATOMIC_RELAXED, __HIP_MEMORY_SCOPE_WORKGROUP);
    if (w == 0){
      asm volatile("s_waitcnt vmcnt(0)" ::: "memory");
      int tries = 0;
      for (;;){
        asm volatile("" ::: "memory");
        int pv = __builtin_nontemporal_load(&xmap[512 + gg*32 + (lane & 31)]);
        if (__all(pv != 0)){ ntok = 1; break; }
        __builtin_amdgcn_s_sleep(1);
        if (++tries > 2048) break;
      }
    }
  }
  // ---- stage 3: group consensus vote ----
  if (tid == 0)
    __hip_atomic_store(&xmap[1024 + gg*32 + r], ntok ? 2 : 1, __ATOMIC_RELAXED, __HIP_MEMORY_SCOPE_AGENT);
  if (w == 0){
    int allfast = 0, vb = 0;
    for (;;){
      int v = __hip_atomic_load(&xmap[1024 + gg*32 + (lane & 31)], __ATOMIC_RELAXED, __HIP_MEMORY_SCOPE_AGENT);
      if (__all(v != 0)){ allfast = (__all(v == 2) ? 1 : 0); break; }
      __builtin_amdgcn_s_sleep(2);
      if (++vb > (1<<18)){ allfast = 0; break; }
    }
    if (tid == 0) s_mode = allfast;
  }
  __syncthreads();
  bool fastnt = (s_mode != 0);

  // gate ownership (waves 0-1 only): rl = tid&7 (local row), cl = tid>>3
  int rl = tid & 7, cl = (tid >> 3) & 15;
  int R = odd*8 + rl;                         // frag row of this block's data
  int rw = (lane >> 4)*4, cw = lane & 15;     // MFMA C-frag position
  float c = 0.f, s1 = 0.f, s2 = 0.f;

  // publish constants: value (rl, hcol=r*16+cl) -> h-frag ushort address
  int kt_w = r >> 1;
  int kk = (r & 1)*16 + cl;
  int sl_w = rl + 8*(kk >> 3);
  size_t du_off = (((size_t)(gg*16 + kt_w)*32 + sl_w)*8 + (kk & 7)) >> 1;
  int* myflag = flags + (gg*32 + r)*16 + w;
  // wait-set: 8 source ranks x 2 publishing waves (lanes 0-15, dup above)
  const int* fwp = flags + (gg*32 + 8*w + ((lane & 15) >> 1))*16 + (lane & 1);

  int sl_r = (lane & 7) + 8*(lane >> 4);      // reader slot (rows 8-15 dup)

  const s16x8* xv8 = (const s16x8*)xin;
  const s16x8* hvr = (const s16x8*)hex;
  unsigned int* hvw = (unsigned int*)hex;

  // prefetch x fragments for t=0
  s16x8 xa[4];
  if (LAYER == 1){
    const s16x8* ax = xv8 + (q*16 + 4*w)*64 + lane;
#pragma unroll
    for (int i = 0; i < 4; i++) xa[i] = ax[i*64];
  } else {
    const s16x8* ax = xv8 + (size_t)gg*512 + (4*w)*32 + sl_r;
#pragma unroll
    for (int i = 0; i < 4; i++) xa[i] = ax[i*32];
  }

  for (int t = 0; t < T_STEPS; t++){
    f32x4 acc[4];
#pragma unroll
    for (int n = 0; n < 4; n++) acc[n] = (f32x4){0.f,0.f,0.f,0.f};
    // X phase (independent of recurrence)
#pragma unroll
    for (int ki = 0; ki < 4; ki++)
#pragma unroll
      for (int n = 0; n < 4; n++)
        acc[n] = __builtin_amdgcn_mfma_f32_16x16x32_bf16(xa[ki], B[ki][n], acc[n], 0,0,0);
    // prefetch next step's x while waiting
    if (t + 1 < T_STEPS){
      if (LAYER == 1){
        const s16x8* ax = xv8 + (size_t)(t+1)*8192 + (q*16 + 4*w)*64 + lane;
#pragma unroll
        for (int i = 0; i < 4; i++) xa[i] = ax[i*64];
      } else {
        const s16x8* ax = xv8 + ((size_t)(t+1)*16 + gg)*512 + (4*w)*32 + sl_r;
#pragma unroll
        for (int i = 0; i < 4; i++) xa[i] = ax[i*32];
      }
    }
    if (t > 0){
      int bail = 0;
      if (fastnt){
        for (;;){
          asm volatile("" ::: "memory");
          int f = __builtin_nontemporal_load(fwp);
          if (__all(f >= t)) break;
          __builtin_amdgcn_s_sleep(1);
          if (++bail > (1<<14)) break;
        }
      } else {
        for (;;){
          int f = __hip_atomic_load(fwp, __ATOMIC_RELAXED, __HIP_MEMORY_SCOPE_AGENT);
          if (__all(f >= t)) break;
          __builtin_amdgcn_s_sleep(2);
          if (++bail > (1<<14)) break;
        }
      }
      asm volatile("" ::: "memory");
      const s16x8* ah = hvr + ((size_t)(t-1)*16 + gg)*512 + (4*w)*32 + sl_r;
      s16x8 h0 = ah[0], h1 = ah[32], h2 = ah[64], h3 = ah[96];
#pragma unroll
      for (int n = 0; n < 4; n++) acc[n] = __builtin_amdgcn_mfma_f32_16x16x32_bf16(h0, B[4][n], acc[n], 0,0,0);
#pragma unroll
      for (int n = 0; n < 4; n++) acc[n] = __builtin_amdgcn_mfma_f32_16x16x32_bf16(h1, B[5][n], acc[n], 0,0,0);
#pragma unroll
      for (int n = 0; n < 4; n++) acc[n] = __builtin_amdgcn_mfma_f32_16x16x32_bf16(h2, B[6][n], acc[n], 0,0,0);
#pragma unroll
      for (int n = 0; n < 4; n++) acc[n] = __builtin_amdgcn_mfma_f32_16x16x32_bf16(h3, B[7][n], acc[n], 0,0,0);
    }
    // zone stores (double-buffered; pitch 20 floats)
    float* zb = zs[t & 1];
#pragma unroll
    for (int n = 0; n < 4; n++)
      *(f32x4*)&zb[(w*64 + n*16 + cw)*20 + rw] = acc[n];
    __syncthreads();
    // gate math + publish: waves 0-1, thread owns (row R, hcol = r*16+cl)
    if (tid < 128){
      float z4[4];
#pragma unroll
      for (int n = 0; n < 4; n++){
        z4[n] = zb[(      n*16 + cl)*20 + R]
              + zb[( 64 + n*16 + cl)*20 + R]
              + zb[(128 + n*16 + cl)*20 + R]
              + zb[(192 + n*16 + cl)*20 + R]
              + blds[n*16 + cl];
      }
      float gi = fsig(z4[0]), gf = fsig(z4[1]), gg2 = ftanh(z4[2]), go = fsig(z4[3]);
      c = gf*c + gi*gg2;
      float h = go * ftanh(c);
      if (LAYER == 1){ s1 += h; s2 += h*h; }
      if (LAYER == 2 && t == T_STEPS-1) aux[(size_t)(gg*8 + rl)*512 + r*16 + cl] = h;
      // pair (cl, cl+1) into one dword; even-cl threads store
      unsigned hv = f2bf(h);
      unsigned other = (unsigned)__shfl_down((int)hv, 8);
      if ((lane & 8) == 0){
        unsigned w32v = hv | (other << 16);
        unsigned int* dst = hvw + (size_t)t*(TS_US/2) + du_off;
        if (fastp) *dst = w32v;
        else __hip_atomic_store(dst, w32v, __ATOMIC_RELAXED, __HIP_MEMORY_SCOPE_AGENT);
      }
    }
    asm volatile("s_waitcnt vmcnt(0)" ::: "memory");   // h stores acked
    if (w < 2 && lane == 0){
      if (fastnt)
        __hip_atomic_store(myflag, t+1, __ATOMIC_RELAXED, __HIP_MEMORY_SCOPE_WORKGROUP);
      else
        __hip_atomic_store(myflag, t+1, __ATOMIC_RELAXED, __HIP_MEMORY_SCOPE_AGENT);
    }
  }

  if (LAYER == 1 && tid < 128){
    // reduce stats over the block's 8 rows (clusters of 8 consecutive lanes)
    s1 += __shfl_down(s1, 4); s2 += __shfl_down(s2, 4);
    s1 += __shfl_down(s1, 2); s2 += __shfl_down(s2, 2);
    s1 += __shfl_down(s1, 1); s2 += __shfl_down(s2, 1);
    if ((tid & 7) == 0){
      int ch = r*16 + cl;
      aux[(ch*16 + gg)*2]     = s1;
      aux[(ch*16 + gg)*2 + 1] = s2;
    }
  }
}

// ---------- BN2 + dense head ----------
__global__ __launch_bounds__(512)
void k_epilogue(const float* __restrict__ h2,
                const float* __restrict__ g2, const float* __restrict__ be2,
                const float* __restrict__ Wd1, const float* __restrict__ bd1,
                const float* __restrict__ Wd2, const float* __restrict__ bd2,
                float* __restrict__ out){
  __shared__ float mu[512], rs[512], bb[512];
  __shared__ float t16[128*16];
  int tid = threadIdx.x;
  {
    float s = 0.f, qq = 0.f;
    for (int r = 0; r < 128; r++){ float v = h2[r*512 + tid]; s += v; qq += v*v; }
    float m = s * (1.f/128.f);
    float var = qq * (1.f/128.f) - m*m;
    mu[tid] = m;
    rs[tid] = rsqrtf(fmaxf(var,0.f) + 1e-5f) * g2[tid];
    bb[tid] = be2[tid];
  }
  __syncthreads();
  for (int task = tid; task < 2048; task += 512){
    int b = task >> 4, u = task & 15;
    float acc = bd1[u];
    for (int k = 0; k < 512; k++){
      float hn = (h2[b*512 + k] - mu[k]) * rs[k] + bb[k];
      acc += hn * Wd1[k*16 + u];
    }
    t16[task] = tanhf(acc);
  }
  __syncthreads();
  if (tid < 128){
    float acc = bd2[0];
#pragma unroll
    for (int u = 0; u < 16; u++) acc += t16[tid*16 + u] * Wd2[u];
    out[tid] = acc;
  }
}

extern "C" void kernel_launch(void* const* d_in, const int* in_sizes, int n_in,
                              void* d_out, int out_size, void* d_ws, size_t ws_size,
                              hipStream_t stream){
  const float* x    = (const float*)d_in[0];
  const float* Wi1  = (const float*)d_in[1];
  const float* Wh1  = (const float*)d_in[2];
  const float* b1   = (const float*)d_in[3];
  const float* Wi2  = (const float*)d_in[4];
  const float* Wh2  = (const float*)d_in[5];
  const float* b2   = (const float*)d_in[6];
  const float* g1   = (const float*)d_in[7];
  const float* be1  = (const float*)d_in[8];
  const float* g2   = (const float*)d_in[9];
  const float* be2  = (const float*)d_in[10];
  const float* Wd1  = (const float*)d_in[11];
  const float* bd1  = (const float*)d_in[12];
  const float* Wd2  = (const float*)d_in[13];
  const float* bd2  = (const float*)d_in[14];
  float* out = (float*)d_out;

  char* ws = (char*)d_ws;
  size_t off = 0;
  auto alloc = [&](size_t bytes)->void*{
    void* pp = ws + off; off += (bytes + 255) & ~(size_t)255; return pp;
  };
  unsigned short* xpacked = (unsigned short*)alloc((size_t)512*TS_US*2);  // 64 MiB
  unsigned short* S       = (unsigned short*)alloc((size_t)514*TS_US*2);  // 64.25 MiB
  unsigned short* w1p     = (unsigned short*)alloc((size_t)32*128*64*8*2);
  unsigned short* w2p     = (unsigned short*)alloc((size_t)32*128*64*8*2);
  float* bias1  = (float*)alloc(2048*4);
  float* bias2  = (float*)alloc(2048*4);
  float* stats1 = (float*)alloc((size_t)512*16*2*4);
  int*   flags1 = (int*)alloc(8192*4);
  int*   flags2 = (int*)alloc(8192*4);
  int*   xmap1  = (int*)alloc(2048*4);
  int*   xmap2  = (int*)alloc(2048*4);
  float* h2last = (float*)alloc((size_t)128*512*4);

  if (off > ws_size){
    k_sentinel<<<1, 256, 0, stream>>>(out, out_size, (float)(ws_size >> 20));
    return;
  }

  unsigned short* S2 = S + (size_t)2*TS_US;

  k_reset<<<1, 1024, 0, stream>>>(flags1, flags2, xmap1, xmap2);
  k_pack_x<<<4096, 256, 0, stream>>>(x, xpacked);
  k_pack_w1<<<32, 256, 0, stream>>>(Wi1, Wh1, b1, w1p, bias1);
  k_scan<1><<<512, 256, 0, stream>>>(xpacked, S2, w1p, bias1, flags1, xmap1, stats1);
  k_fold2<<<32, 256, 0, stream>>>(Wi2, Wh2, b2, g1, be1, stats1, w2p, bias2);
  k_scan<2><<<512, 256, 0, stream>>>(S2, xpacked, w2p, bias2, flags2, xmap2, h2last);
  k_epilogue<<<1, 512, 0, stream>>>(h2last, g2, be2, Wd1, bd1, Wd2, bd2, out);
}

// Round 9
// 1998.430 us; speedup vs baseline: 1.0247x; 1.0247x over previous
//
#include <hip/hip_runtime.h>
#include <hip/hip_bf16.h>

#define T_STEPS 512
#define TS_US   65536         // ushorts per t-slot (128KB) for x and h buffers
#define SENT    0x7FC07FC0u   // bf16 NaN pair: h can never equal this

typedef __attribute__((ext_vector_type(4))) float f32x4;
typedef __attribute__((ext_vector_type(8))) short s16x8;
typedef __attribute__((ext_vector_type(4))) unsigned int u32x4;

// ---------- helpers ----------
__device__ __forceinline__ unsigned short f2bf(float f){
  unsigned int u = __float_as_uint(f);
  unsigned int r = (u + 0x7fffu + ((u >> 16) & 1u)) >> 16;
  return (unsigned short)r;
}
__device__ __forceinline__ float fsig(float x){
  return __builtin_amdgcn_rcpf(1.f + __expf(-x));
}
__device__ __forceinline__ float ftanh(float x){
  x = fminf(fmaxf(x, -15.f), 15.f);
  float a = __expf(2.f * x);
  return (a - 1.f) * __builtin_amdgcn_rcpf(a + 1.f);
}
__device__ __forceinline__ s16x8 as_frag(u32x4 v){
  union { u32x4 u; s16x8 s; } c; c.u = v; return c.s;
}

// ---------- pack x into 16-row (q-group) MFMA A-fragment layout ----------
__global__ void k_pack_x(const float* __restrict__ x, unsigned short* __restrict__ xp){
  int t = blockIdx.x >> 3, q = blockIdx.x & 7;
  __shared__ unsigned short xs[16*520];
  int tid = threadIdx.x;
  for (int qq = tid; qq < 1024; qq += 256){
    int rw = qq >> 6, k8 = qq & 63;
    const float* src = x + ((size_t)(q*16 + rw)*512 + t)*512 + k8*8;
    union { unsigned short u[8]; s16x8 v; } tmp;
#pragma unroll
    for (int e = 0; e < 8; e++) tmp.u[e] = f2bf(src[e]);
    *(s16x8*)&xs[rw*520 + k8*8] = tmp.v;
  }
  __syncthreads();
  for (int s = tid; s < 1024; s += 256){
    int kt = s >> 6, ln = s & 63;
    int rw2 = ln & 15, k0 = kt*32 + (ln >> 4)*8;
    s16x8 v = *(const s16x8*)&xs[rw2*520 + k0];
    ((s16x8*)xp)[(size_t)t*8192 + (q*16 + kt)*64 + ln] = v;
  }
}

// ---------- pack layer-1 weights into B-fragment layout ----------
__global__ void k_pack_w1(const float* __restrict__ Wi, const float* __restrict__ Wh,
                          const float* __restrict__ b, unsigned short* __restrict__ wp,
                          float* __restrict__ bias){
  int r = blockIdx.x, tid = threadIdx.x;
  int lane = tid & 63, u0 = tid >> 6;
  for (int ch = u0; ch < 128; ch += 4){
    int kt = ch >> 2, n = ch & 3;
    int col = n*512 + r*16 + (lane & 15);
    int kb = kt*32 + (lane >> 4)*8;
    union { unsigned short u[8]; s16x8 v; } tmp;
#pragma unroll
    for (int e = 0; e < 8; e++){
      int k = kb + e;
      float wv = (kt < 16) ? Wi[(size_t)k*2048 + col] : Wh[(size_t)(k-512)*2048 + col];
      tmp.u[e] = f2bf(wv);
    }
    ((s16x8*)wp)[((size_t)r*128 + ch)*64 + lane] = tmp.v;
  }
  if (tid < 64) bias[r*64 + tid] = b[(tid >> 4)*512 + r*16 + (tid & 15)];
}

// ---------- fold BN1 into Wi2, pack layer-2 weights, fused bias ----------
__global__ void k_fold2(const float* __restrict__ Wi2, const float* __restrict__ Wh2,
                        const float* __restrict__ b2, const float* __restrict__ gamma,
                        const float* __restrict__ beta, const float* __restrict__ stats,
                        unsigned short* __restrict__ wp, float* __restrict__ bias){
  __shared__ float a_s[512], c_s[512], red[256];
  int r = blockIdx.x, tid = threadIdx.x;
  for (int k = tid; k < 512; k += 256){
    float sm = 0.f, sq = 0.f;
#pragma unroll
    for (int g = 0; g < 16; g++){ sm += stats[(k*16+g)*2]; sq += stats[(k*16+g)*2+1]; }
    float mean = sm * (1.f/65536.f);
    float var  = sq * (1.f/65536.f) - mean*mean;
    float rr = rsqrtf(fmaxf(var, 0.f) + 1e-5f);
    float a = rr * gamma[k];
    a_s[k] = a; c_s[k] = beta[k] - mean*a;
  }
  __syncthreads();
  int lane = tid & 63, u0 = tid >> 6;
  for (int ch = u0; ch < 128; ch += 4){
    int kt = ch >> 2, n = ch & 3;
    int col = n*512 + r*16 + (lane & 15);
    int kb = kt*32 + (lane >> 4)*8;
    union { unsigned short u[8]; s16x8 v; } tmp;
#pragma unroll
    for (int e = 0; e < 8; e++){
      int k = kb + e;
      float wv = (kt < 16) ? a_s[k]*Wi2[(size_t)k*2048 + col]
                           : Wh2[(size_t)(k-512)*2048 + col];
      tmp.u[e] = f2bf(wv);
    }
    ((s16x8*)wp)[((size_t)r*128 + ch)*64 + lane] = tmp.v;
  }
  int colj = tid >> 2, part = tid & 3;
  int n = colj >> 4, cl = colj & 15;
  int col = n*512 + r*16 + cl;
  float s = 0.f;
  for (int k = part*128; k < part*128 + 128; k++) s += c_s[k]*Wi2[(size_t)k*2048 + col];
  red[tid] = s;
  __syncthreads();
  if (part == 0)
    bias[r*64 + colj] = b2[col] + red[tid] + red[tid+1] + red[tid+2] + red[tid+3];
}

__global__ void k_reset(int* f1, int* f2, int* x1, int* x2){
  int t = threadIdx.x;
  for (int i = t; i < 8192; i += 1024){ f1[i] = 0; f2[i] = 0; }
  for (int i = t; i < 2048; i += 1024){ x1[i] = 0; x2[i] = 0; }
}

// fill a region with the bf16-NaN sentinel (n in uint4 units)
__global__ void k_fill(unsigned int* __restrict__ p, long n){
  u32x4 v = {SENT, SENT, SENT, SENT};
  u32x4* q = (u32x4*)p;
  long i = (long)blockIdx.x*blockDim.x + threadIdx.x;
  long stride = (long)gridDim.x*blockDim.x;
  for (; i < n; i += stride) q[i] = v;
}

__global__ void k_sentinel(float* out, int n, float v){
  int i = blockIdx.x * blockDim.x + threadIdx.x;
  if (i < n) out[i] = v;
}

// ---------- persistent group-local LSTM scan (flagless data-poll edition) ----
// 512 blocks x 256 threads. 16 groups x 8 batch rows; gg = blockIdx&15,
// r = blockIdx>>4 (group's 32 ranks share one XCD; 2 groups/XCD, 2 blocks/CU).
// DATAPOLL mode (fastp + nt-probe + group consensus): h-exchange slots are
// write-once and pre-filled with bf16-NaN sentinel; consumers poll the h DATA
// itself with nt-loads (L1-bypass, r7-probe-proven) and use the loaded values
// directly. Removes from the critical path: producer vmcnt(0) ack, flag store,
// flag visibility hop, and the separate poll->load double hop. Publish becomes
// fire-and-forget dword stores (each dword self-validates; no ordering needed).
// Fallback (probe/vote fails): round-8 flag mechanism, bit-exact.
// x-prefetch moved AFTER detect so the poll's vmcnt never waits on it.
template<int LAYER>
__global__ __launch_bounds__(256, 2)
void k_scan(const unsigned short* __restrict__ xin, unsigned short* __restrict__ hex,
            const unsigned short* __restrict__ wp, const float* __restrict__ bias,
            int* __restrict__ flags, int* __restrict__ xmap, float* __restrict__ aux){
  __shared__ __align__(16) float zs[2][4*64*20];
  __shared__ float blds[64];
  __shared__ int s_mode;
  int gg = blockIdx.x & 15, r = blockIdx.x >> 4;
  int q = gg >> 1, odd = gg & 1;
  int tid = threadIdx.x, w = tid >> 6, lane = tid & 63;

  // weight fragments -> registers/AGPRs (volatile: load exactly once)
  const volatile s16x8* wpv = (const volatile s16x8*)((const s16x8*)wp + (size_t)r*128*64);
  s16x8 B[8][4];
#pragma unroll
  for (int ki = 0; ki < 8; ki++){
    int kt = (ki < 4) ? (4*w + ki) : (12 + 4*w + ki);
#pragma unroll
    for (int n = 0; n < 4; n++)
      B[ki][n] = wpv[((size_t)kt*4 + n)*64 + lane];
  }
  if (tid < 64) blds[tid] = bias[r*64 + tid];

  // ---- stage 1: XCD uniformity handshake ----
  int myx;
  asm volatile("s_getreg_b32 %0, hwreg(HW_REG_XCC_ID)" : "=s"(myx));
  if (tid == 0)
    __hip_atomic_store(&xmap[gg*32 + r], (myx & 0xff) + 1, __ATOMIC_RELAXED, __HIP_MEMORY_SCOPE_AGENT);
  int xv, hb = 0;
  for (;;){
    xv = __hip_atomic_load(&xmap[gg*32 + (lane & 31)], __ATOMIC_RELAXED, __HIP_MEMORY_SCOPE_AGENT);
    if (__all(xv != 0)) break;
    __builtin_amdgcn_s_sleep(2);
    if (++hb > (1<<16)) break;
  }
  int xv0 = __builtin_amdgcn_readfirstlane(xv);
  bool fastp = __all(xv != 0 && xv == xv0) != 0;

  // ---- stage 2: nt-visibility probe (plain store -> nt load) ----
  int ntok = 0;
  if (fastp){
    if (tid == 0)
      __hip_atomic_store(&xmap[512 + gg*32 + r], r + 1, __ATOMIC_RELAXED, __HIP_MEMORY_SCOPE_WORKGROUP);
    if (w == 0){
      asm volatile("s_waitcnt vmcnt(0)" ::: "memory");
      int tries = 0;
      for (;;){
        asm volatile("" ::: "memory");
        int pv = __builtin_nontemporal_load(&xmap[512 + gg*32 + (lane & 31)]);
        if (__all(pv != 0)){ ntok = 1; break; }
        __builtin_amdgcn_s_sleep(1);
        if (++tries > 2048) break;
      }
    }
  }
  // ---- stage 3: group consensus vote (agent atomics, always works) ----
  if (tid == 0)
    __hip_atomic_store(&xmap[1024 + gg*32 + r], ntok ? 2 : 1, __ATOMIC_RELAXED, __HIP_MEMORY_SCOPE_AGENT);
  if (w == 0){
    int allfast = 0, vb = 0;
    for (;;){
      int v = __hip_atomic_load(&xmap[1024 + gg*32 + (lane & 31)], __ATOMIC_RELAXED, __HIP_MEMORY_SCOPE_AGENT);
      if (__all(v != 0)){ allfast = (__all(v == 2) ? 1 : 0); break; }
      __builtin_amdgcn_s_sleep(2);
      if (++vb > (1<<18)){ allfast = 0; break; }
    }
    if (tid == 0) s_mode = allfast;
  }
  __syncthreads();
  bool dpoll = (s_mode != 0);   // implies fastp

  // gate ownership (waves 0-1 only): rl = tid&7 (local row), cl = tid>>3
  int rl = tid & 7, cl = (tid >> 3) & 15;
  int R = odd*8 + rl;
  int rw = (lane >> 4)*4, cw = lane & 15;
  float c = 0.f, s1 = 0.f, s2 = 0.f;

  int kt_w = r >> 1;
  int kk = (r & 1)*16 + cl;
  int sl_w = rl + 8*(kk >> 3);
  size_t du_off = (((size_t)(gg*16 + kt_w)*32 + sl_w)*8 + (kk & 7)) >> 1;
  int* myflag = flags + (gg*32 + r)*16 + w;
  const int* fwp = flags + (gg*32 + 8*w + ((lane & 15) >> 1))*16 + (lane & 1);

  int sl_r = (lane & 7) + 8*(lane >> 4);

  const s16x8* xv8 = (const s16x8*)xin;
  const s16x8* hvr = (const s16x8*)hex;
  unsigned int* hvw = (unsigned int*)hex;

  // prefetch x fragments for t=0
  s16x8 xa[4];
  if (LAYER == 1){
    const s16x8* ax = xv8 + (q*16 + 4*w)*64 + lane;
#pragma unroll
    for (int i = 0; i < 4; i++) xa[i] = ax[i*64];
  } else {
    const s16x8* ax = xv8 + (size_t)gg*512 + (4*w)*32 + sl_r;
#pragma unroll
    for (int i = 0; i < 4; i++) xa[i] = ax[i*32];
  }

  for (int t = 0; t < T_STEPS; t++){
    f32x4 acc[4];
#pragma unroll
    for (int n = 0; n < 4; n++) acc[n] = (f32x4){0.f,0.f,0.f,0.f};
    // X phase (independent of recurrence)
#pragma unroll
    for (int ki = 0; ki < 4; ki++)
#pragma unroll
      for (int n = 0; n < 4; n++)
        acc[n] = __builtin_amdgcn_mfma_f32_16x16x32_bf16(xa[ki], B[ki][n], acc[n], 0,0,0);

    if (t > 0){
      s16x8 h0, h1, h2, h3;
      if (dpoll){
        // ---- flagless detect: poll the h data itself for non-sentinel ----
        const u32x4* ap = (const u32x4*)(hvr + ((size_t)(t-1)*16 + gg)*512 + (4*w)*32 + sl_r);
        u32x4 f0, f1, f2, f3;
        int bail = 0;
        for (;;){
          asm volatile("" ::: "memory");
          f0 = __builtin_nontemporal_load(ap);
          f1 = __builtin_nontemporal_load(ap + 32);
          f2 = __builtin_nontemporal_load(ap + 64);
          f3 = __builtin_nontemporal_load(ap + 96);
          bool ok = true;
#pragma unroll
          for (int i = 0; i < 4; i++)
            ok = ok && (f0[i] != SENT) && (f1[i] != SENT) && (f2[i] != SENT) && (f3[i] != SENT);
          if (__all(ok)) break;
          if (++bail > (1<<12)) break;   // bounded: fail visibly, never hang
        }
        h0 = as_frag(f0); h1 = as_frag(f1); h2 = as_frag(f2); h3 = as_frag(f3);
      } else {
        // ---- round-8 flag path ----
        int bail = 0;
        for (;;){
          int f = __hip_atomic_load(fwp, __ATOMIC_RELAXED, __HIP_MEMORY_SCOPE_AGENT);
          if (__all(f >= t)) break;
          __builtin_amdgcn_s_sleep(2);
          if (++bail > (1<<14)) break;
        }
        asm volatile("" ::: "memory");
        const s16x8* ah = hvr + ((size_t)(t-1)*16 + gg)*512 + (4*w)*32 + sl_r;
        h0 = ah[0]; h1 = ah[32]; h2 = ah[64]; h3 = ah[96];
      }
      // x-prefetch for t+1 AFTER detect (off the poll's vmcnt drain)
      if (t + 1 < T_STEPS){
        if (LAYER == 1){
          const s16x8* ax = xv8 + (size_t)(t+1)*8192 + (q*16 + 4*w)*64 + lane;
#pragma unroll
          for (int i = 0; i < 4; i++) xa[i] = ax[i*64];
        } else {
          const s16x8* ax = xv8 + ((size_t)(t+1)*16 + gg)*512 + (4*w)*32 + sl_r;
#pragma unroll
          for (int i = 0; i < 4; i++) xa[i] = ax[i*32];
        }
      }
#pragma unroll
      for (int n = 0; n < 4; n++) acc[n] = __builtin_amdgcn_mfma_f32_16x16x32_bf16(h0, B[4][n], acc[n], 0,0,0);
#pragma unroll
      for (int n = 0; n < 4; n++) acc[n] = __builtin_amdgcn_mfma_f32_16x16x32_bf16(h1, B[5][n], acc[n], 0,0,0);
#pragma unroll
      for (int n = 0; n < 4; n++) acc[n] = __builtin_amdgcn_mfma_f32_16x16x32_bf16(h2, B[6][n], acc[n], 0,0,0);
#pragma unroll
      for (int n = 0; n < 4; n++) acc[n] = __builtin_amdgcn_mfma_f32_16x16x32_bf16(h3, B[7][n], acc[n], 0,0,0);
    } else {
      if (t + 1 < T_STEPS){
        if (LAYER == 1){
          const s16x8* ax = xv8 + (size_t)(t+1)*8192 + (q*16 + 4*w)*64 + lane;
#pragma unroll
          for (int i = 0; i < 4; i++) xa[i] = ax[i*64];
        } else {
          const s16x8* ax = xv8 + ((size_t)(t+1)*16 + gg)*512 + (4*w)*32 + sl_r;
#pragma unroll
          for (int i = 0; i < 4; i++) xa[i] = ax[i*32];
        }
      }
    }
    // zone stores (double-buffered; pitch 20 floats)
    float* zb = zs[t & 1];
#pragma unroll
    for (int n = 0; n < 4; n++)
      *(f32x4*)&zb[(w*64 + n*16 + cw)*20 + rw] = acc[n];
    __syncthreads();
    // gate math + publish: waves 0-1, thread owns (row R, hcol = r*16+cl)
    if (tid < 128){
      float z4[4];
#pragma unroll
      for (int n = 0; n < 4; n++){
        z4[n] = zb[(      n*16 + cl)*20 + R]
              + zb[( 64 + n*16 + cl)*20 + R]
              + zb[(128 + n*16 + cl)*20 + R]
              + zb[(192 + n*16 + cl)*20 + R]
              + blds[n*16 + cl];
      }
      float gi = fsig(z4[0]), gf = fsig(z4[1]), gg2 = ftanh(z4[2]), go = fsig(z4[3]);
      c = gf*c + gi*gg2;
      float h = go * ftanh(c);
      if (LAYER == 1){ s1 += h; s2 += h*h; }
      if (LAYER == 2 && t == T_STEPS-1) aux[(size_t)(gg*8 + rl)*512 + r*16 + cl] = h;
      unsigned hv = f2bf(h);
      unsigned other = (unsigned)__shfl_down((int)hv, 8);
      if ((lane & 8) == 0){
        unsigned w32v = hv | (other << 16);
        unsigned int* dst = hvw + (size_t)t*(TS_US/2) + du_off;
        if (fastp) *dst = w32v;        // fire-and-forget; dword self-validates
        else __hip_atomic_store(dst, w32v, __ATOMIC_RELAXED, __HIP_MEMORY_SCOPE_AGENT);
      }
    }
    if (!dpoll){
      asm volatile("s_waitcnt vmcnt(0)" ::: "memory");
      if (w < 2 && lane == 0)
        __hip_atomic_store(myflag, t+1, __ATOMIC_RELAXED, __HIP_MEMORY_SCOPE_AGENT);
    }
  }

  if (LAYER == 1 && tid < 128){
    s1 += __shfl_down(s1, 4); s2 += __shfl_down(s2, 4);
    s1 += __shfl_down(s1, 2); s2 += __shfl_down(s2, 2);
    s1 += __shfl_down(s1, 1); s2 += __shfl_down(s2, 1);
    if ((tid & 7) == 0){
      int ch = r*16 + cl;
      aux[(ch*16 + gg)*2]     = s1;
      aux[(ch*16 + gg)*2 + 1] = s2;
    }
  }
}

// ---------- BN2 + dense head ----------
__global__ __launch_bounds__(512)
void k_epilogue(const float* __restrict__ h2,
                const float* __restrict__ g2, const float* __restrict__ be2,
                const float* __restrict__ Wd1, const float* __restrict__ bd1,
                const float* __restrict__ Wd2, const float* __restrict__ bd2,
                float* __restrict__ out){
  __shared__ float mu[512], rs[512], bb[512];
  __shared__ float t16[128*16];
  int tid = threadIdx.x;
  {
    float s = 0.f, qq = 0.f;
    for (int r = 0; r < 128; r++){ float v = h2[r*512 + tid]; s += v; qq += v*v; }
    float m = s * (1.f/128.f);
    float var = qq * (1.f/128.f) - m*m;
    mu[tid] = m;
    rs[tid] = rsqrtf(fmaxf(var,0.f) + 1e-5f) * g2[tid];
    bb[tid] = be2[tid];
  }
  __syncthreads();
  for (int task = tid; task < 2048; task += 512){
    int b = task >> 4, u = task & 15;
    float acc = bd1[u];
    for (int k = 0; k < 512; k++){
      float hn = (h2[b*512 + k] - mu[k]) * rs[k] + bb[k];
      acc += hn * Wd1[k*16 + u];
    }
    t16[task] = tanhf(acc);
  }
  __syncthreads();
  if (tid < 128){
    float acc = bd2[0];
#pragma unroll
    for (int u = 0; u < 16; u++) acc += t16[tid*16 + u] * Wd2[u];
    out[tid] = acc;
  }
}

extern "C" void kernel_launch(void* const* d_in, const int* in_sizes, int n_in,
                              void* d_out, int out_size, void* d_ws, size_t ws_size,
                              hipStream_t stream){
  const float* x    = (const float*)d_in[0];
  const float* Wi1  = (const float*)d_in[1];
  const float* Wh1  = (const float*)d_in[2];
  const float* b1   = (const float*)d_in[3];
  const float* Wi2  = (const float*)d_in[4];
  const float* Wh2  = (const float*)d_in[5];
  const float* b2   = (const float*)d_in[6];
  const float* g1   = (const float*)d_in[7];
  const float* be1  = (const float*)d_in[8];
  const float* g2   = (const float*)d_in[9];
  const float* be2  = (const float*)d_in[10];
  const float* Wd1  = (const float*)d_in[11];
  const float* bd1  = (const float*)d_in[12];
  const float* Wd2  = (const float*)d_in[13];
  const float* bd2  = (const float*)d_in[14];
  float* out = (float*)d_out;

  char* ws = (char*)d_ws;
  size_t off = 0;
  auto alloc = [&](size_t bytes)->void*{
    void* pp = ws + off; off += (bytes + 255) & ~(size_t)255; return pp;
  };
  unsigned short* xpacked = (unsigned short*)alloc((size_t)512*TS_US*2);  // 64 MiB
  unsigned short* S       = (unsigned short*)alloc((size_t)514*TS_US*2);  // 64.25 MiB
  unsigned short* w1p     = (unsigned short*)alloc((size_t)32*128*64*8*2);
  unsigned short* w2p     = (unsigned short*)alloc((size_t)32*128*64*8*2);
  float* bias1  = (float*)alloc(2048*4);
  float* bias2  = (float*)alloc(2048*4);
  float* stats1 = (float*)alloc((size_t)512*16*2*4);
  int*   flags1 = (int*)alloc(8192*4);
  int*   flags2 = (int*)alloc(8192*4);
  int*   xmap1  = (int*)alloc(2048*4);
  int*   xmap2  = (int*)alloc(2048*4);
  float* h2last = (float*)alloc((size_t)128*512*4);

  if (off > ws_size){
    k_sentinel<<<1, 256, 0, stream>>>(out, out_size, (float)(ws_size >> 20));
    return;
  }

  unsigned short* S2 = S + (size_t)2*TS_US;

  k_reset<<<1, 1024, 0, stream>>>(flags1, flags2, xmap1, xmap2);
  // NaN-fill layer-1's h-exchange buffer (write-once slots; data-poll detect)
  k_fill<<<2048, 256, 0, stream>>>((unsigned int*)S, (long)514*TS_US/8);
  k_pack_x<<<4096, 256, 0, stream>>>(x, xpacked);
  k_pack_w1<<<32, 256, 0, stream>>>(Wi1, Wh1, b1, w1p, bias1);
  k_scan<1><<<512, 256, 0, stream>>>(xpacked, S2, w1p, bias1, flags1, xmap1, stats1);
  k_fold2<<<32, 256, 0, stream>>>(Wi2, Wh2, b2, g1, be1, stats1, w2p, bias2);
  // NaN-fill layer-2's h-exchange buffer (xpacked reused; scan1 has fully read it)
  k_fill<<<2048, 256, 0, stream>>>((unsigned int*)xpacked, (long)512*TS_US/8);
  k_scan<2><<<512, 256, 0, stream>>>(S2, xpacked, w2p, bias2, flags2, xmap2, h2last);
  k_epilogue<<<1, 512, 0, stream>>>(h2last, g2, be2, Wd1, bd1, Wd2, bd2, out);
}